// Round 2
// baseline (99.204 us; speedup 1.0000x reference)
//
#include <hip/hip_runtime.h>

#define L_SEQ 4096
#define BATCH 2
#define NHEAD 4
#define DHEAD 32
#define DMODEL 128
#define CH 16            // kv tiles (of 64) per chunk -> <=4 chunks per q-tile

typedef __attribute__((ext_vector_type(4))) float floatx4;
typedef __attribute__((ext_vector_type(8))) __bf16 bf16x8;
typedef __attribute__((ext_vector_type(8))) unsigned short ushort8;
typedef __attribute__((ext_vector_type(2))) unsigned short ushort2v;

__device__ __forceinline__ floatx4 MFMA(ushort8 a, ushort8 b, floatx4 c) {
  return __builtin_amdgcn_mfma_f32_16x16x32_bf16(
      __builtin_bit_cast(bf16x8, a), __builtin_bit_cast(bf16x8, b), c, 0, 0, 0);
}

__device__ __forceinline__ unsigned short f2bf(float f) {
  union { float f; unsigned int u; } x; x.f = f;
  unsigned int u = x.u + 0x7fffu + ((x.u >> 16) & 1u);   // RNE truncate
  return (unsigned short)(u >> 16);
}

// ---------------------------------------------------------------------------
// Kernel 1: fused QKV projection.  out = x @ W^T + b  (Q also * 1/sqrt(32))
// Q,K stored [b*4+h][L][32] bf16 ; V stored transposed [b*4+h][32][L] bf16.
// ---------------------------------------------------------------------------
#define WLDS 136

__global__ __launch_bounds__(256) void proj_kernel(
    const float* __restrict__ xq, const float* __restrict__ xk,
    const float* __restrict__ xv,
    const float* __restrict__ WQ, const float* __restrict__ bQ,
    const float* __restrict__ WK, const float* __restrict__ bK,
    const float* __restrict__ WV, const float* __restrict__ bV,
    unsigned short* __restrict__ Qs, unsigned short* __restrict__ Ks,
    unsigned short* __restrict__ Vt)
{
  __shared__ unsigned short Wl[128 * WLDS];
  __shared__ float bl[128];
  const int mat = blockIdx.z;
  const int b   = blockIdx.y;
  const int l0  = blockIdx.x * 64;
  const float* __restrict__ x    = (mat == 0) ? xq : (mat == 1) ? xk : xv;
  const float* __restrict__ W    = (mat == 0) ? WQ : (mat == 1) ? WK : WV;
  const float* __restrict__ bias = (mat == 0) ? bQ : (mat == 1) ? bK : bV;
  const int tid = threadIdx.x;

  #pragma unroll
  for (int it = 0; it < 16; ++it) {
    int idx = tid + it * 256;
    int row = idx >> 5;
    int col = (idx & 31) * 4;
    floatx4 v = *(const floatx4*)(W + row * 128 + col);
    unsigned short* dst = Wl + row * WLDS + col;
    dst[0] = f2bf(v[0]); dst[1] = f2bf(v[1]);
    dst[2] = f2bf(v[2]); dst[3] = f2bf(v[3]);
  }
  if (tid < 128) bl[tid] = bias[tid];
  __syncthreads();

  const int w = tid >> 6, lane = tid & 63;
  const int g = lane >> 4, qi = lane & 15;

  ushort8 xf[4];
  #pragma unroll
  for (int kk = 0; kk < 4; ++kk) {
    const float* src = x + ((size_t)(l0 + w * 16 + qi) * BATCH + b) * DMODEL + kk * 32 + g * 8;
    floatx4 a = *(const floatx4*)src;
    floatx4 c = *(const floatx4*)(src + 4);
    ushort8 f;
    f[0]=f2bf(a[0]); f[1]=f2bf(a[1]); f[2]=f2bf(a[2]); f[3]=f2bf(a[3]);
    f[4]=f2bf(c[0]); f[5]=f2bf(c[1]); f[6]=f2bf(c[2]); f[7]=f2bf(c[3]);
    xf[kk] = f;
  }

  floatx4 acc[8];
  #pragma unroll
  for (int n = 0; n < 8; ++n) acc[n] = (floatx4){0.f, 0.f, 0.f, 0.f};

  #pragma unroll
  for (int kk = 0; kk < 4; ++kk) {
    #pragma unroll
    for (int n = 0; n < 8; ++n) {
      ushort8 wf = *(const ushort8*)(Wl + (n * 16 + qi) * WLDS + kk * 32 + g * 8);
      acc[n] = (mat == 2) ? MFMA(wf, xf[kk], acc[n]) : MFMA(xf[kk], wf, acc[n]);
    }
  }

  const int hb4 = b * NHEAD;
  if (mat < 2) {
    unsigned short* __restrict__ outp = (mat == 0) ? Qs : Ks;
    const float scale = (mat == 0) ? 0.17677669529663687f : 1.0f;
    #pragma unroll
    for (int n = 0; n < 8; ++n) {
      int c = n * 16 + qi;
      int h = c >> 5, dh = c & 31;
      float bb = bl[c];
      #pragma unroll
      for (int r = 0; r < 4; ++r) {
        int lq = l0 + w * 16 + 4 * g + r;
        float v = (acc[n][r] + bb) * scale;
        outp[((size_t)(hb4 + h) * L_SEQ + lq) * DHEAD + dh] = f2bf(v);
      }
    }
  } else {
    #pragma unroll
    for (int n = 0; n < 8; ++n) {
      #pragma unroll
      for (int r = 0; r < 4; ++r) {
        int cout = n * 16 + 4 * g + r;
        int h = cout >> 5, dh = cout & 31;
        float v = acc[n][r] + bl[cout];
        int lq = l0 + w * 16 + qi;
        Vt[((size_t)(hb4 + h) * DHEAD + dh) * L_SEQ + lq] = f2bf(v);
      }
    }
  }
}

// ---------------------------------------------------------------------------
// Kernel 2: KV-split flash attention, barrier-free.
// Grid (256, 8): x = tq + 64*c (c = kv chunk of CH tiles), y = plane (b*4+h).
// No K/V LDS staging (L2-resident); per-wave P roundtrip LDS only.
// Partials (m, l, O) per (plane, tq, c) go to ws; combine_kernel merges.
// ---------------------------------------------------------------------------
#define PPAD 72

__global__ __launch_bounds__(256, 4) void attn_kernel(
    const unsigned short* __restrict__ Qs, const unsigned short* __restrict__ Ks,
    const unsigned short* __restrict__ Vt,
    float* __restrict__ Opart, float* __restrict__ MLpart)
{
  const int tq = blockIdx.x & 63;
  const int c  = blockIdx.x >> 6;
  if (c * CH > tq) return;                 // chunk beyond causal range
  const int t0   = c * CH;
  const int tend = min(t0 + CH, tq + 1);
  const int hb = blockIdx.y;

  __shared__ unsigned short Plds[4 * 16 * PPAD];

  const int tid = threadIdx.x;
  const int w = tid >> 6, lane = tid & 63;
  const int g = lane >> 4, qi = lane & 15;

  const unsigned short* __restrict__ Qh = Qs + (size_t)hb * L_SEQ * DHEAD;
  const unsigned short* __restrict__ Kh = Ks + (size_t)hb * L_SEQ * DHEAD;
  const unsigned short* __restrict__ Vh = Vt + (size_t)hb * DHEAD * L_SEQ;

  ushort8 qf = *(const ushort8*)(Qh + (size_t)(tq * 64 + w * 16 + qi) * DHEAD + g * 8);

  floatx4 cc[2];
  cc[0] = (floatx4){0.f, 0.f, 0.f, 0.f};
  cc[1] = (floatx4){0.f, 0.f, 0.f, 0.f};
  float m = -1e30f, l = 0.f;

  unsigned short* Pw = Plds + w * 16 * PPAD;

  ushort8 kc[4], kn[4], vc[2][2];

  // K fragment load: lane (qi,g) holds K[t*64+tt*16+qi][8g..8g+7]
  auto loadK = [&](int t, ushort8 (&kk)[4]) {
    #pragma unroll
    for (int tt = 0; tt < 4; ++tt)
      kk[tt] = *(const ushort8*)(Kh + (size_t)(t * 64 + tt * 16 + qi) * DHEAD + g * 8);
  };
  // V^T fragment load: lane (qi,g) holds V^T[nt*16+qi][t*64 + kh*32 + 8g ..]
  auto loadV = [&](int t, ushort8 (&vv)[2][2]) {
    #pragma unroll
    for (int nt = 0; nt < 2; ++nt)
      #pragma unroll
      for (int kh = 0; kh < 2; ++kh)
        vv[nt][kh] = *(const ushort8*)(Vh + (size_t)(nt * 16 + qi) * L_SEQ + t * 64 + kh * 32 + g * 8);
  };

  loadK(t0, kc);

  for (int t = t0; t < tend; ++t) {
    loadV(t, vc);                      // consumed late (after softmax) -> latency hides
    if (t + 1 < tend) loadK(t + 1, kn);

    // QK^T (swapped): s[tt] = K_tile^T-frag x Q -> S^T[kv=16tt+4g+r][q=qi]
    floatx4 s[4];
    __builtin_amdgcn_s_setprio(1);
    #pragma unroll
    for (int tt = 0; tt < 4; ++tt)
      s[tt] = MFMA(kc[tt], qf, (floatx4){0.f, 0.f, 0.f, 0.f});
    __builtin_amdgcn_s_setprio(0);

    float vmax = -1e30f;
    #pragma unroll
    for (int tt = 0; tt < 4; ++tt)
      vmax = fmaxf(vmax, fmaxf(fmaxf(s[tt][0], s[tt][1]), fmaxf(s[tt][2], s[tt][3])));
    vmax = fmaxf(vmax, __shfl_xor(vmax, 16));
    vmax = fmaxf(vmax, __shfl_xor(vmax, 32));
    float mnew = fmaxf(m, vmax);
    float corr = __expf(m - mnew);
    m = mnew;
    float rsum = 0.f;
    #pragma unroll
    for (int tt = 0; tt < 4; ++tt) {
      float p0 = __expf(s[tt][0] - mnew);
      float p1 = __expf(s[tt][1] - mnew);
      float p2 = __expf(s[tt][2] - mnew);
      float p3 = __expf(s[tt][3] - mnew);
      rsum += (p0 + p1) + (p2 + p3);
      ushort2v w0, w1;
      w0[0] = f2bf(p0); w0[1] = f2bf(p1);
      w1[0] = f2bf(p2); w1[1] = f2bf(p3);
      *(ushort2v*)(Pw + qi * PPAD + tt * 16 + g * 4)     = w0;
      *(ushort2v*)(Pw + qi * PPAD + tt * 16 + g * 4 + 2) = w1;
    }
    rsum += __shfl_xor(rsum, 16);
    rsum += __shfl_xor(rsum, 32);
    l = l * corr + rsum;
    float c0 = __shfl(corr, 4 * g + 0);
    float c1 = __shfl(corr, 4 * g + 1);
    float c2 = __shfl(corr, 4 * g + 2);
    float c3 = __shfl(corr, 4 * g + 3);
    cc[0][0] *= c0; cc[0][1] *= c1; cc[0][2] *= c2; cc[0][3] *= c3;
    cc[1][0] *= c0; cc[1][1] *= c1; cc[1][2] *= c2; cc[1][3] *= c3;

    // cross-lane RAW on Plds (per-wave buffer): HW drain + compiler barrier
    asm volatile("s_waitcnt lgkmcnt(0)" ::: "memory");
    ushort8 pa0 = *(const ushort8*)(Pw + qi * PPAD + g * 8);
    ushort8 pa1 = *(const ushort8*)(Pw + qi * PPAD + 32 + g * 8);
    asm volatile("" ::: "memory");

    __builtin_amdgcn_s_setprio(1);
    cc[0] = MFMA(pa0, vc[0][0], cc[0]);
    cc[0] = MFMA(pa1, vc[0][1], cc[0]);
    cc[1] = MFMA(pa0, vc[1][0], cc[1]);
    cc[1] = MFMA(pa1, vc[1][1], cc[1]);
    __builtin_amdgcn_s_setprio(0);

    #pragma unroll
    for (int tt = 0; tt < 4; ++tt) kc[tt] = kn[tt];
  }

  // write partials: O[q][dh] (unnormalized), ml[q]
  const int slot = (hb * 64 + tq) * 4 + c;
  float* __restrict__ Op = Opart + (size_t)slot * 2048;
  float* __restrict__ Ml = MLpart + (size_t)slot * 128;
  if (g == 0) {
    Ml[(w * 16 + qi) * 2 + 0] = m;
    Ml[(w * 16 + qi) * 2 + 1] = l;
  }
  #pragma unroll
  for (int nt = 0; nt < 2; ++nt)
    #pragma unroll
    for (int r = 0; r < 4; ++r)
      Op[(w * 16 + 4 * g + r) * 32 + nt * 16 + qi] = cc[nt][r];
}

// ---------------------------------------------------------------------------
// Kernel 2b: combine partials -> ctx bf16 [B][L][128]
// Grid (64, 8), 256 threads: thread = (q row 0..63) x (dh-group of 8)
// ---------------------------------------------------------------------------
__global__ __launch_bounds__(256) void combine_kernel(
    const float* __restrict__ Opart, const float* __restrict__ MLpart,
    unsigned short* __restrict__ ctx)
{
  const int tq = blockIdx.x;
  const int hb = blockIdx.y;
  const int nc = (tq >> 4) + 1;
  const int tid = threadIdx.x;
  const int q  = tid >> 2;
  const int dg = tid & 3;
  const int slot0 = (hb * 64 + tq) * 4;

  float mv[4], lv[4];
  float M = -1e30f;
  #pragma unroll
  for (int ci = 0; ci < 4; ++ci) {
    if (ci < nc) {
      mv[ci] = MLpart[(size_t)(slot0 + ci) * 128 + q * 2 + 0];
      lv[ci] = MLpart[(size_t)(slot0 + ci) * 128 + q * 2 + 1];
      M = fmaxf(M, mv[ci]);
    }
  }
  float Lsum = 0.f;
  float wgt[4];
  #pragma unroll
  for (int ci = 0; ci < 4; ++ci) {
    if (ci < nc) {
      wgt[ci] = __expf(mv[ci] - M);
      Lsum += wgt[ci] * lv[ci];
    }
  }
  float inv = 1.0f / Lsum;

  floatx4 a0 = (floatx4){0.f,0.f,0.f,0.f}, a1 = (floatx4){0.f,0.f,0.f,0.f};
  #pragma unroll
  for (int ci = 0; ci < 4; ++ci) {
    if (ci < nc) {
      const float* Op = Opart + (size_t)(slot0 + ci) * 2048 + q * 32 + dg * 8;
      floatx4 o0 = *(const floatx4*)(Op);
      floatx4 o1 = *(const floatx4*)(Op + 4);
      float wv = wgt[ci];
      a0 += wv * o0;
      a1 += wv * o1;
    }
  }
  const int b = hb >> 2, hh = hb & 3;
  size_t base = ((size_t)b * L_SEQ + tq * 64 + q) * DMODEL + hh * 32 + dg * 8;
  #pragma unroll
  for (int j = 0; j < 4; ++j) {
    ctx[base + j]     = f2bf(a0[j] * inv);
    ctx[base + 4 + j] = f2bf(a1[j] * inv);
  }
}

// ---------------------------------------------------------------------------
// Kernel 3: output projection  out = ctx @ W_O^T + b_O  (f32 out)
// ---------------------------------------------------------------------------
__global__ __launch_bounds__(256) void oproj_kernel(
    const unsigned short* __restrict__ ctx, const float* __restrict__ WO,
    const float* __restrict__ bO, float* __restrict__ out)
{
  __shared__ unsigned short Wl[128 * WLDS];
  __shared__ float bl[128];
  const int m0 = blockIdx.x * 64;
  const int tid = threadIdx.x;

  #pragma unroll
  for (int it = 0; it < 16; ++it) {
    int idx = tid + it * 256;
    int row = idx >> 5, col = (idx & 31) * 4;
    floatx4 v = *(const floatx4*)(WO + row * 128 + col);
    unsigned short* dst = Wl + row * WLDS + col;
    dst[0] = f2bf(v[0]); dst[1] = f2bf(v[1]);
    dst[2] = f2bf(v[2]); dst[3] = f2bf(v[3]);
  }
  if (tid < 128) bl[tid] = bO[tid];
  __syncthreads();

  const int w = tid >> 6, lane = tid & 63;
  const int g = lane >> 4, qi = lane & 15;

  ushort8 xf[4];
  #pragma unroll
  for (int kk = 0; kk < 4; ++kk)
    xf[kk] = *(const ushort8*)(ctx + (size_t)(m0 + w * 16 + qi) * DMODEL + kk * 32 + g * 8);

  floatx4 acc[8];
  #pragma unroll
  for (int n = 0; n < 8; ++n) acc[n] = (floatx4){0.f, 0.f, 0.f, 0.f};

  #pragma unroll
  for (int kk = 0; kk < 4; ++kk) {
    #pragma unroll
    for (int n = 0; n < 8; ++n) {
      ushort8 wf = *(const ushort8*)(Wl + (n * 16 + qi) * WLDS + kk * 32 + g * 8);
      acc[n] = MFMA(xf[kk], wf, acc[n]);
    }
  }

  #pragma unroll
  for (int n = 0; n < 8; ++n) {
    int c = n * 16 + qi;
    float bb = bl[c];
    #pragma unroll
    for (int r = 0; r < 4; ++r) {
      int m = m0 + w * 16 + 4 * g + r;
      out[(size_t)m * DMODEL + c] = acc[n][r] + bb;
    }
  }
}

// ---------------------------------------------------------------------------
extern "C" void kernel_launch(void* const* d_in, const int* in_sizes, int n_in,
                              void* d_out, int out_size, void* d_ws, size_t ws_size,
                              hipStream_t stream) {
  const float* q  = (const float*)d_in[0];
  const float* k  = (const float*)d_in[1];
  const float* v  = (const float*)d_in[2];
  const float* WQ = (const float*)d_in[3];
  const float* bQ = (const float*)d_in[4];
  const float* WK = (const float*)d_in[5];
  const float* bK = (const float*)d_in[6];
  const float* WV = (const float*)d_in[7];
  const float* bV = (const float*)d_in[8];
  const float* WO = (const float*)d_in[9];
  const float* bO = (const float*)d_in[10];
  float* out = (float*)d_out;

  const size_t plane = (size_t)BATCH * NHEAD * L_SEQ * DHEAD;  // 1,048,576 ush
  unsigned short* Qs  = (unsigned short*)d_ws;
  unsigned short* Ks  = Qs + plane;
  unsigned short* Vt  = Ks + plane;
  unsigned short* ctx = Vt + plane;                 // [B][L][128] bf16 (1M ush)
  float* Opart  = (float*)(ctx + plane);            // 2048 slots x 64 x 32 f32
  float* MLpart = Opart + (size_t)2048 * 2048;      // 2048 slots x 64 x 2 f32

  hipLaunchKernelGGL(proj_kernel, dim3(64, 2, 3), dim3(256), 0, stream,
                     q, k, v, WQ, bQ, WK, bK, WV, bV, Qs, Ks, Vt);
  hipLaunchKernelGGL(attn_kernel, dim3(256, 8), dim3(256), 0, stream,
                     Qs, Ks, Vt, Opart, MLpart);
  hipLaunchKernelGGL(combine_kernel, dim3(64, 8), dim3(256), 0, stream,
                     Opart, MLpart, ctx);
  hipLaunchKernelGGL(oproj_kernel, dim3(128), dim3(256), 0, stream, ctx, WO, bO, out);
}

// Round 3
// 79.130 us; speedup vs baseline: 1.2537x; 1.2537x over previous
//
#include <hip/hip_runtime.h>

#define L_SEQ 4096
#define BATCH 2
#define NHEAD 4
#define DHEAD 32
#define DMODEL 128
#define CH 16            // kv tiles (of 64) per chunk -> <=4 chunks per q-tile

typedef __attribute__((ext_vector_type(4))) float floatx4;
typedef __attribute__((ext_vector_type(16))) float floatx16;
typedef __attribute__((ext_vector_type(8))) __bf16 bf16x8;
typedef __attribute__((ext_vector_type(8))) unsigned short ushort8;
typedef __attribute__((ext_vector_type(4))) unsigned short ushort4v;
typedef __attribute__((ext_vector_type(4))) unsigned int uintx4;

__device__ __forceinline__ floatx4 MFMA(ushort8 a, ushort8 b, floatx4 c) {
  return __builtin_amdgcn_mfma_f32_16x16x32_bf16(
      __builtin_bit_cast(bf16x8, a), __builtin_bit_cast(bf16x8, b), c, 0, 0, 0);
}
__device__ __forceinline__ floatx16 MFMA32(ushort8 a, ushort8 b, floatx16 c) {
  return __builtin_amdgcn_mfma_f32_32x32x16_bf16(
      __builtin_bit_cast(bf16x8, a), __builtin_bit_cast(bf16x8, b), c, 0, 0, 0);
}

__device__ __forceinline__ unsigned short f2bf(float f) {
  union { float f; unsigned int u; } x; x.f = f;
  unsigned int u = x.u + 0x7fffu + ((x.u >> 16) & 1u);   // RNE truncate
  return (unsigned short)(u >> 16);
}

__device__ __forceinline__ unsigned pkbf(float lo, float hi) {
  unsigned r;
  asm("v_cvt_pk_bf16_f32 %0, %1, %2" : "=v"(r) : "v"(lo), "v"(hi));
  return r;
}

// ---------------------------------------------------------------------------
// Kernel 1: fused QKV projection.  out = x @ W^T + b  (Q also * 1/sqrt(32))
// Q,K stored [b*4+h][L][32] bf16 ; V stored transposed [b*4+h][32][L] bf16.
// ---------------------------------------------------------------------------
#define WLDS 136

__global__ __launch_bounds__(256) void proj_kernel(
    const float* __restrict__ xq, const float* __restrict__ xk,
    const float* __restrict__ xv,
    const float* __restrict__ WQ, const float* __restrict__ bQ,
    const float* __restrict__ WK, const float* __restrict__ bK,
    const float* __restrict__ WV, const float* __restrict__ bV,
    unsigned short* __restrict__ Qs, unsigned short* __restrict__ Ks,
    unsigned short* __restrict__ Vt)
{
  __shared__ unsigned short Wl[128 * WLDS];
  __shared__ float bl[128];
  const int mat = blockIdx.z;
  const int b   = blockIdx.y;
  const int l0  = blockIdx.x * 64;
  const float* __restrict__ x    = (mat == 0) ? xq : (mat == 1) ? xk : xv;
  const float* __restrict__ W    = (mat == 0) ? WQ : (mat == 1) ? WK : WV;
  const float* __restrict__ bias = (mat == 0) ? bQ : (mat == 1) ? bK : bV;
  const int tid = threadIdx.x;

  #pragma unroll
  for (int it = 0; it < 16; ++it) {
    int idx = tid + it * 256;
    int row = idx >> 5;
    int col = (idx & 31) * 4;
    floatx4 v = *(const floatx4*)(W + row * 128 + col);
    unsigned short* dst = Wl + row * WLDS + col;
    dst[0] = f2bf(v[0]); dst[1] = f2bf(v[1]);
    dst[2] = f2bf(v[2]); dst[3] = f2bf(v[3]);
  }
  if (tid < 128) bl[tid] = bias[tid];
  __syncthreads();

  const int w = tid >> 6, lane = tid & 63;
  const int g = lane >> 4, qi = lane & 15;

  ushort8 xf[4];
  #pragma unroll
  for (int kk = 0; kk < 4; ++kk) {
    const float* src = x + ((size_t)(l0 + w * 16 + qi) * BATCH + b) * DMODEL + kk * 32 + g * 8;
    floatx4 a = *(const floatx4*)src;
    floatx4 c = *(const floatx4*)(src + 4);
    ushort8 f;
    f[0]=f2bf(a[0]); f[1]=f2bf(a[1]); f[2]=f2bf(a[2]); f[3]=f2bf(a[3]);
    f[4]=f2bf(c[0]); f[5]=f2bf(c[1]); f[6]=f2bf(c[2]); f[7]=f2bf(c[3]);
    xf[kk] = f;
  }

  floatx4 acc[8];
  #pragma unroll
  for (int n = 0; n < 8; ++n) acc[n] = (floatx4){0.f, 0.f, 0.f, 0.f};

  #pragma unroll
  for (int kk = 0; kk < 4; ++kk) {
    #pragma unroll
    for (int n = 0; n < 8; ++n) {
      ushort8 wf = *(const ushort8*)(Wl + (n * 16 + qi) * WLDS + kk * 32 + g * 8);
      acc[n] = (mat == 2) ? MFMA(wf, xf[kk], acc[n]) : MFMA(xf[kk], wf, acc[n]);
    }
  }

  const int hb4 = b * NHEAD;
  if (mat < 2) {
    unsigned short* __restrict__ outp = (mat == 0) ? Qs : Ks;
    const float scale = (mat == 0) ? 0.17677669529663687f : 1.0f;
    #pragma unroll
    for (int n = 0; n < 8; ++n) {
      int c = n * 16 + qi;
      int h = c >> 5, dh = c & 31;
      float bb = bl[c];
      #pragma unroll
      for (int r = 0; r < 4; ++r) {
        int lq = l0 + w * 16 + 4 * g + r;
        float v = (acc[n][r] + bb) * scale;
        outp[((size_t)(hb4 + h) * L_SEQ + lq) * DHEAD + dh] = f2bf(v);
      }
    }
  } else {
    #pragma unroll
    for (int n = 0; n < 8; ++n) {
      #pragma unroll
      for (int r = 0; r < 4; ++r) {
        int cout = n * 16 + 4 * g + r;
        int h = cout >> 5, dh = cout & 31;
        float v = acc[n][r] + bl[cout];
        int lq = l0 + w * 16 + qi;
        Vt[((size_t)(hb4 + h) * DHEAD + dh) * L_SEQ + lq] = f2bf(v);
      }
    }
  }
}

// ---------------------------------------------------------------------------
// Kernel 2: KV-split flash attention, 32x32 MFMA, fully lane-local softmax.
// Each WAVE is an independent work item: (plane, 32-q half, chunk of <=16 kv
// tiles). Swapped QK^T (mfma(K,Q)) -> lane owns one q column (q = lane&31).
// PV as O^T = V^T x P with a permuted kv order so P needs NO lane exchange.
// Grid (40, 16): x*4+wave = chunk id (0..159), y = plane*2 + half.
// ---------------------------------------------------------------------------
__global__ __launch_bounds__(256, 4) void attn_kernel(
    const unsigned short* __restrict__ Qs, const unsigned short* __restrict__ Ks,
    const unsigned short* __restrict__ Vt,
    float* __restrict__ Opart, float* __restrict__ MLpart)
{
  __shared__ float Tr[4][32 * 36];   // per-wave transpose scratch

  const int tid = threadIdx.x;
  const int w = tid >> 6, lane = tid & 63;
  const int ql = lane & 31, hi = lane >> 5;

  const int cid   = blockIdx.x * 4 + w;      // 0..159
  const int plane = blockIdx.y >> 1;
  const int half  = blockIdx.y & 1;

  int c, tq;
  if (cid < 64)       { c = 0; tq = cid; }
  else if (cid < 112) { c = 1; tq = cid - 48; }
  else if (cid < 144) { c = 2; tq = cid - 80; }
  else                { c = 3; tq = cid - 96; }
  const int t0   = c * CH;
  const int tend = min(t0 + CH, tq + 1);

  const unsigned short* __restrict__ Qh = Qs + (size_t)plane * L_SEQ * DHEAD;
  const unsigned short* __restrict__ Kh = Ks + (size_t)plane * L_SEQ * DHEAD;
  const unsigned short* __restrict__ Vh = Vt + (size_t)plane * DHEAD * L_SEQ;

  const int q0 = tq * 64 + half * 32;
  // Q B-frags: lane holds Q[q0+ql][dhalf*16 + hi*8 + 0..7]
  ushort8 qf0 = *(const ushort8*)(Qh + (size_t)(q0 + ql) * DHEAD + hi * 8);
  ushort8 qf1 = *(const ushort8*)(Qh + (size_t)(q0 + ql) * DHEAD + 16 + hi * 8);

  const floatx16 z16 = {0,0,0,0,0,0,0,0,0,0,0,0,0,0,0,0};
  floatx16 acc = z16;          // O^T[dh=(r&3)+8*(r>>2)+4*hi][q=ql]
  float m = -1e30f, l = 0.f;

  // per-lane base pointers (advance per tile)
  const unsigned short* kp = Kh + ((size_t)t0 * 64 + ql) * DHEAD + hi * 8;
  const unsigned short* vp = Vh + (size_t)ql * L_SEQ + t0 * 64 + hi * 4;

  for (int t = t0; t < tend; ++t) {
    // ---- loads (K: 4x16B, V: 8x8B) issued up front ----
    ushort8 kf00 = *(const ushort8*)(kp);               // kg0, d 0..15
    ushort8 kf01 = *(const ushort8*)(kp + 16);          // kg0, d 16..31
    ushort8 kf10 = *(const ushort8*)(kp + 1024);        // kg1, d 0..15
    ushort8 kf11 = *(const ushort8*)(kp + 1024 + 16);   // kg1, d 16..31
    ushort4v v00a = *(const ushort4v*)(vp);             // kg0 sub0: kv' 4hi+0..3
    ushort4v v00b = *(const ushort4v*)(vp + 8);         //          kv' 4hi+8..11
    ushort4v v01a = *(const ushort4v*)(vp + 16);        // kg0 sub1
    ushort4v v01b = *(const ushort4v*)(vp + 24);
    ushort4v v10a = *(const ushort4v*)(vp + 32);        // kg1 sub0
    ushort4v v10b = *(const ushort4v*)(vp + 40);
    ushort4v v11a = *(const ushort4v*)(vp + 48);        // kg1 sub1
    ushort4v v11b = *(const ushort4v*)(vp + 56);
    kp += 64 * DHEAD;
    vp += 64;

    // ---- QK^T: St[kg][row kv'=(r&3)+8*(r>>2)+4*hi][col q=ql] ----
    floatx16 St0 = MFMA32(kf00, qf0, z16);
    St0 = MFMA32(kf01, qf1, St0);
    floatx16 St1 = MFMA32(kf10, qf0, z16);
    St1 = MFMA32(kf11, qf1, St1);

    // ---- lane-local softmax (column q = ql) ----
    float pmax = St0[0];
    #pragma unroll
    for (int i = 1; i < 16; ++i) pmax = fmaxf(pmax, St0[i]);
    #pragma unroll
    for (int i = 0; i < 16; ++i) pmax = fmaxf(pmax, St1[i]);
    pmax = fmaxf(pmax, __shfl_xor(pmax, 32));

    if (__any(pmax > m + 8.0f)) {            // defer-max (THR=8)
      float mnew = fmaxf(m, pmax);
      float corr = __expf(m - mnew);
      m = mnew;
      l *= corr;
      #pragma unroll
      for (int i = 0; i < 16; ++i) acc[i] *= corr;
    }
    float rsum = 0.f;
    #pragma unroll
    for (int i = 0; i < 16; ++i) { float e = __expf(St0[i] - m); St0[i] = e; rsum += e; }
    #pragma unroll
    for (int i = 0; i < 16; ++i) { float e = __expf(St1[i] - m); St1[i] = e; rsum += e; }
    rsum += __shfl_xor(rsum, 32);
    l += rsum;

    // ---- pack P (own lanes only; kv order permuted to match V frags) ----
    uintx4 pb;
    ushort8 va;
    // kg0 sub0: p rows St0[0..7]
    pb[0] = pkbf(St0[0], St0[1]); pb[1] = pkbf(St0[2], St0[3]);
    pb[2] = pkbf(St0[4], St0[5]); pb[3] = pkbf(St0[6], St0[7]);
    va = __builtin_shufflevector(v00a, v00b, 0,1,2,3,4,5,6,7);
    acc = MFMA32(va, __builtin_bit_cast(ushort8, pb), acc);
    // kg0 sub1: St0[8..15]
    pb[0] = pkbf(St0[8], St0[9]);  pb[1] = pkbf(St0[10], St0[11]);
    pb[2] = pkbf(St0[12], St0[13]); pb[3] = pkbf(St0[14], St0[15]);
    va = __builtin_shufflevector(v01a, v01b, 0,1,2,3,4,5,6,7);
    acc = MFMA32(va, __builtin_bit_cast(ushort8, pb), acc);
    // kg1 sub0: St1[0..7]
    pb[0] = pkbf(St1[0], St1[1]); pb[1] = pkbf(St1[2], St1[3]);
    pb[2] = pkbf(St1[4], St1[5]); pb[3] = pkbf(St1[6], St1[7]);
    va = __builtin_shufflevector(v10a, v10b, 0,1,2,3,4,5,6,7);
    acc = MFMA32(va, __builtin_bit_cast(ushort8, pb), acc);
    // kg1 sub1: St1[8..15]
    pb[0] = pkbf(St1[8], St1[9]);  pb[1] = pkbf(St1[10], St1[11]);
    pb[2] = pkbf(St1[12], St1[13]); pb[3] = pkbf(St1[14], St1[15]);
    va = __builtin_shufflevector(v11a, v11b, 0,1,2,3,4,5,6,7);
    acc = MFMA32(va, __builtin_bit_cast(ushort8, pb), acc);
  }

  // ---- epilogue: transpose O^T -> O via LDS, write f32 partials ----
  const int slot = ((plane * 64 + tq) * 4 + c);
  float* T = &Tr[w][0];
  #pragma unroll
  for (int r = 0; r < 16; ++r) {
    int dh = (r & 3) + 8 * (r >> 2) + 4 * hi;
    T[ql * 36 + dh] = acc[r];
  }
  asm volatile("s_waitcnt lgkmcnt(0)" ::: "memory");
  __builtin_amdgcn_sched_barrier(0);

  const int qr = lane >> 1, dg = (lane & 1) * 16;
  float* __restrict__ Op = Opart + (size_t)slot * 2048 + half * 32 * 32;
  #pragma unroll
  for (int j = 0; j < 4; ++j) {
    floatx4 vv = *(const floatx4*)(T + qr * 36 + dg + 4 * j);
    *(floatx4*)(Op + qr * 32 + dg + 4 * j) = vv;
  }
  if (hi == 0) {
    MLpart[(size_t)slot * 128 + (half * 32 + ql) * 2 + 0] = m;
    MLpart[(size_t)slot * 128 + (half * 32 + ql) * 2 + 1] = l;
  }
}

// ---------------------------------------------------------------------------
// Kernel 2b: combine partials -> ctx bf16 [B][L][128]
// ---------------------------------------------------------------------------
__global__ __launch_bounds__(256) void combine_kernel(
    const float* __restrict__ Opart, const float* __restrict__ MLpart,
    unsigned short* __restrict__ ctx)
{
  const int tq = blockIdx.x;
  const int hb = blockIdx.y;
  const int nc = (tq >> 4) + 1;
  const int tid = threadIdx.x;
  const int q  = tid >> 2;
  const int dg = tid & 3;
  const int slot0 = (hb * 64 + tq) * 4;

  float mv[4], lv[4];
  float M = -1e30f;
  #pragma unroll
  for (int ci = 0; ci < 4; ++ci) {
    if (ci < nc) {
      mv[ci] = MLpart[(size_t)(slot0 + ci) * 128 + q * 2 + 0];
      lv[ci] = MLpart[(size_t)(slot0 + ci) * 128 + q * 2 + 1];
      M = fmaxf(M, mv[ci]);
    }
  }
  float Lsum = 0.f;
  float wgt[4];
  #pragma unroll
  for (int ci = 0; ci < 4; ++ci) {
    if (ci < nc) {
      wgt[ci] = __expf(mv[ci] - M);
      Lsum += wgt[ci] * lv[ci];
    }
  }
  float inv = 1.0f / Lsum;

  floatx4 a0 = (floatx4){0.f,0.f,0.f,0.f}, a1 = (floatx4){0.f,0.f,0.f,0.f};
  #pragma unroll
  for (int ci = 0; ci < 4; ++ci) {
    if (ci < nc) {
      const float* Op = Opart + (size_t)(slot0 + ci) * 2048 + q * 32 + dg * 8;
      floatx4 o0 = *(const floatx4*)(Op);
      floatx4 o1 = *(const floatx4*)(Op + 4);
      float wv = wgt[ci];
      a0 += wv * o0;
      a1 += wv * o1;
    }
  }
  const int b = hb >> 2, hh = hb & 3;
  size_t base = ((size_t)b * L_SEQ + tq * 64 + q) * DMODEL + hh * 32 + dg * 8;
  #pragma unroll
  for (int j = 0; j < 4; ++j) {
    ctx[base + j]     = f2bf(a0[j] * inv);
    ctx[base + 4 + j] = f2bf(a1[j] * inv);
  }
}

// ---------------------------------------------------------------------------
// Kernel 3: output projection  out = ctx @ W_O^T + b_O  (f32 out)
// ---------------------------------------------------------------------------
__global__ __launch_bounds__(256) void oproj_kernel(
    const unsigned short* __restrict__ ctx, const float* __restrict__ WO,
    const float* __restrict__ bO, float* __restrict__ out)
{
  __shared__ unsigned short Wl[128 * WLDS];
  __shared__ float bl[128];
  const int m0 = blockIdx.x * 64;
  const int tid = threadIdx.x;

  #pragma unroll
  for (int it = 0; it < 16; ++it) {
    int idx = tid + it * 256;
    int row = idx >> 5, col = (idx & 31) * 4;
    floatx4 v = *(const floatx4*)(WO + row * 128 + col);
    unsigned short* dst = Wl + row * WLDS + col;
    dst[0] = f2bf(v[0]); dst[1] = f2bf(v[1]);
    dst[2] = f2bf(v[2]); dst[3] = f2bf(v[3]);
  }
  if (tid < 128) bl[tid] = bO[tid];
  __syncthreads();

  const int w = tid >> 6, lane = tid & 63;
  const int g = lane >> 4, qi = lane & 15;

  ushort8 xf[4];
  #pragma unroll
  for (int kk = 0; kk < 4; ++kk)
    xf[kk] = *(const ushort8*)(ctx + (size_t)(m0 + w * 16 + qi) * DMODEL + kk * 32 + g * 8);

  floatx4 acc[8];
  #pragma unroll
  for (int n = 0; n < 8; ++n) acc[n] = (floatx4){0.f, 0.f, 0.f, 0.f};

  #pragma unroll
  for (int kk = 0; kk < 4; ++kk) {
    #pragma unroll
    for (int n = 0; n < 8; ++n) {
      ushort8 wf = *(const ushort8*)(Wl + (n * 16 + qi) * WLDS + kk * 32 + g * 8);
      acc[n] = MFMA(xf[kk], wf, acc[n]);
    }
  }

  #pragma unroll
  for (int n = 0; n < 8; ++n) {
    int c = n * 16 + qi;
    float bb = bl[c];
    #pragma unroll
    for (int r = 0; r < 4; ++r) {
      int m = m0 + w * 16 + 4 * g + r;
      out[(size_t)m * DMODEL + c] = acc[n][r] + bb;
    }
  }
}

// ---------------------------------------------------------------------------
extern "C" void kernel_launch(void* const* d_in, const int* in_sizes, int n_in,
                              void* d_out, int out_size, void* d_ws, size_t ws_size,
                              hipStream_t stream) {
  const float* q  = (const float*)d_in[0];
  const float* k  = (const float*)d_in[1];
  const float* v  = (const float*)d_in[2];
  const float* WQ = (const float*)d_in[3];
  const float* bQ = (const float*)d_in[4];
  const float* WK = (const float*)d_in[5];
  const float* bK = (const float*)d_in[6];
  const float* WV = (const float*)d_in[7];
  const float* bV = (const float*)d_in[8];
  const float* WO = (const float*)d_in[9];
  const float* bO = (const float*)d_in[10];
  float* out = (float*)d_out;

  const size_t plane = (size_t)BATCH * NHEAD * L_SEQ * DHEAD;  // 1,048,576 ush
  unsigned short* Qs  = (unsigned short*)d_ws;
  unsigned short* Ks  = Qs + plane;
  unsigned short* Vt  = Ks + plane;
  unsigned short* ctx = Vt + plane;                 // [B][L][128] bf16 (1M ush)
  float* Opart  = (float*)(ctx + plane);            // 2048 slots x 64 x 32 f32
  float* MLpart = Opart + (size_t)2048 * 2048;      // 2048 slots x 64 x 2 f32

  hipLaunchKernelGGL(proj_kernel, dim3(64, 2, 3), dim3(256), 0, stream,
                     q, k, v, WQ, bQ, WK, bK, WV, bV, Qs, Ks, Vt);
  hipLaunchKernelGGL(attn_kernel, dim3(40, 16), dim3(256), 0, stream,
                     Qs, Ks, Vt, Opart, MLpart);
  hipLaunchKernelGGL(combine_kernel, dim3(64, 8), dim3(256), 0, stream,
                     Opart, MLpart, ctx);
  hipLaunchKernelGGL(oproj_kernel, dim3(128), dim3(256), 0, stream, ctx, WO, bO, out);
}

// Round 8
// 78.906 us; speedup vs baseline: 1.2572x; 1.0028x over previous
//
#include <hip/hip_runtime.h>

#define L_SEQ 4096
#define BATCH 2
#define NHEAD 4
#define DHEAD 32
#define DMODEL 128
#define CH 16            // kv tiles (of 64) per chunk -> <=4 chunks per q-tile

typedef __attribute__((ext_vector_type(4))) float floatx4;
typedef __attribute__((ext_vector_type(16))) float floatx16;
typedef __attribute__((ext_vector_type(8))) __bf16 bf16x8;
typedef __attribute__((ext_vector_type(8))) unsigned short ushort8;
typedef __attribute__((ext_vector_type(4))) unsigned short ushort4v;
typedef __attribute__((ext_vector_type(4))) unsigned int uintx4;

__device__ __forceinline__ floatx4 MFMA(ushort8 a, ushort8 b, floatx4 c) {
  return __builtin_amdgcn_mfma_f32_16x16x32_bf16(
      __builtin_bit_cast(bf16x8, a), __builtin_bit_cast(bf16x8, b), c, 0, 0, 0);
}
__device__ __forceinline__ floatx16 MFMA32(ushort8 a, ushort8 b, floatx16 c) {
  return __builtin_amdgcn_mfma_f32_32x32x16_bf16(
      __builtin_bit_cast(bf16x8, a), __builtin_bit_cast(bf16x8, b), c, 0, 0, 0);
}

__device__ __forceinline__ unsigned short f2bf(float f) {
  union { float f; unsigned int u; } x; x.f = f;
  unsigned int u = x.u + 0x7fffu + ((x.u >> 16) & 1u);   // RNE truncate
  return (unsigned short)(u >> 16);
}

__device__ __forceinline__ unsigned pkbf(float lo, float hi) {
  unsigned r;
  asm("v_cvt_pk_bf16_f32 %0, %1, %2" : "=v"(r) : "v"(lo), "v"(hi));
  return r;
}

// ---------------------------------------------------------------------------
// Kernel 1: fused QKV projection.  out = x @ W^T + b  (Q also * 1/sqrt(32))
// Q,K stored [b*4+h][L][32] bf16 ; V stored transposed [b*4+h][32][L] bf16.
// ---------------------------------------------------------------------------
#define WLDS 136

__global__ __launch_bounds__(256) void proj_kernel(
    const float* __restrict__ xq, const float* __restrict__ xk,
    const float* __restrict__ xv,
    const float* __restrict__ WQ, const float* __restrict__ bQ,
    const float* __restrict__ WK, const float* __restrict__ bK,
    const float* __restrict__ WV, const float* __restrict__ bV,
    unsigned short* __restrict__ Qs, unsigned short* __restrict__ Ks,
    unsigned short* __restrict__ Vt)
{
  __shared__ unsigned short Wl[128 * WLDS];
  __shared__ float bl[128];
  const int mat = blockIdx.z;
  const int b   = blockIdx.y;
  const int l0  = blockIdx.x * 64;
  const float* __restrict__ x    = (mat == 0) ? xq : (mat == 1) ? xk : xv;
  const float* __restrict__ W    = (mat == 0) ? WQ : (mat == 1) ? WK : WV;
  const float* __restrict__ bias = (mat == 0) ? bQ : (mat == 1) ? bK : bV;
  const int tid = threadIdx.x;

  #pragma unroll
  for (int it = 0; it < 16; ++it) {
    int idx = tid + it * 256;
    int row = idx >> 5;
    int col = (idx & 31) * 4;
    floatx4 v = *(const floatx4*)(W + row * 128 + col);
    unsigned short* dst = Wl + row * WLDS + col;
    dst[0] = f2bf(v[0]); dst[1] = f2bf(v[1]);
    dst[2] = f2bf(v[2]); dst[3] = f2bf(v[3]);
  }
  if (tid < 128) bl[tid] = bias[tid];
  __syncthreads();

  const int w = tid >> 6, lane = tid & 63;
  const int g = lane >> 4, qi = lane & 15;

  ushort8 xf[4];
  #pragma unroll
  for (int kk = 0; kk < 4; ++kk) {
    const float* src = x + ((size_t)(l0 + w * 16 + qi) * BATCH + b) * DMODEL + kk * 32 + g * 8;
    floatx4 a = *(const floatx4*)src;
    floatx4 c = *(const floatx4*)(src + 4);
    ushort8 f;
    f[0]=f2bf(a[0]); f[1]=f2bf(a[1]); f[2]=f2bf(a[2]); f[3]=f2bf(a[3]);
    f[4]=f2bf(c[0]); f[5]=f2bf(c[1]); f[6]=f2bf(c[2]); f[7]=f2bf(c[3]);
    xf[kk] = f;
  }

  floatx4 acc[8];
  #pragma unroll
  for (int n = 0; n < 8; ++n) acc[n] = (floatx4){0.f, 0.f, 0.f, 0.f};

  #pragma unroll
  for (int kk = 0; kk < 4; ++kk) {
    #pragma unroll
    for (int n = 0; n < 8; ++n) {
      ushort8 wf = *(const ushort8*)(Wl + (n * 16 + qi) * WLDS + kk * 32 + g * 8);
      acc[n] = (mat == 2) ? MFMA(wf, xf[kk], acc[n]) : MFMA(xf[kk], wf, acc[n]);
    }
  }

  const int hb4 = b * NHEAD;
  if (mat < 2) {
    unsigned short* __restrict__ outp = (mat == 0) ? Qs : Ks;
    const float scale = (mat == 0) ? 0.17677669529663687f : 1.0f;  // 32^-0.5
    #pragma unroll
    for (int n = 0; n < 8; ++n) {
      int c = n * 16 + qi;
      int h = c >> 5, dh = c & 31;
      float bb = bl[c];
      #pragma unroll
      for (int r = 0; r < 4; ++r) {
        int lq = l0 + w * 16 + 4 * g + r;
        float v = (acc[n][r] + bb) * scale;
        outp[((size_t)(hb4 + h) * L_SEQ + lq) * DHEAD + dh] = f2bf(v);
      }
    }
  } else {
    #pragma unroll
    for (int n = 0; n < 8; ++n) {
      #pragma unroll
      for (int r = 0; r < 4; ++r) {
        int cout = n * 16 + 4 * g + r;
        int h = cout >> 5, dh = cout & 31;
        float v = acc[n][r] + bl[cout];
        int lq = l0 + w * 16 + qi;
        Vt[((size_t)(hb4 + h) * DHEAD + dh) * L_SEQ + lq] = f2bf(v);
      }
    }
  }
}

// ---------------------------------------------------------------------------
// Kernel 2: KV-split flash attention, 32x32 MFMA, fully lane-local softmax.
// Each WAVE is an independent work item: (plane, 32-q half, chunk of <=16 kv
// tiles). Swapped QK^T (mfma(K,Q)) -> lane owns one q column (q = lane&31).
// PV as O^T = V^T x P with a permuted kv order so P needs NO lane exchange.
// Grid (40, 16): x*4+wave = chunk id (0..159), y = plane*2 + half.
// ---------------------------------------------------------------------------
__global__ __launch_bounds__(256, 4) void attn_kernel(
    const unsigned short* __restrict__ Qs, const unsigned short* __restrict__ Ks,
    const unsigned short* __restrict__ Vt,
    float* __restrict__ Opart, float* __restrict__ MLpart)
{
  __shared__ float Tr[4][32 * 36];   // per-wave transpose scratch

  const int tid = threadIdx.x;
  const int w = tid >> 6, lane = tid & 63;
  const int ql = lane & 31, hi = lane >> 5;

  const int cid   = blockIdx.x * 4 + w;      // 0..159
  const int plane = blockIdx.y >> 1;
  const int half  = blockIdx.y & 1;

  int c, tq;
  if (cid < 64)       { c = 0; tq = cid; }
  else if (cid < 112) { c = 1; tq = cid - 48; }
  else if (cid < 144) { c = 2; tq = cid - 80; }
  else                { c = 3; tq = cid - 96; }
  const int t0   = c * CH;
  const int tend = min(t0 + CH, tq + 1);

  const unsigned short* __restrict__ Qh = Qs + (size_t)plane * L_SEQ * DHEAD;
  const unsigned short* __restrict__ Kh = Ks + (size_t)plane * L_SEQ * DHEAD;
  const unsigned short* __restrict__ Vh = Vt + (size_t)plane * DHEAD * L_SEQ;

  const int q0 = tq * 64 + half * 32;
  // Q B-frags: lane holds Q[q0+ql][dhalf*16 + hi*8 + 0..7]
  ushort8 qf0 = *(const ushort8*)(Qh + (size_t)(q0 + ql) * DHEAD + hi * 8);
  ushort8 qf1 = *(const ushort8*)(Qh + (size_t)(q0 + ql) * DHEAD + 16 + hi * 8);

  const floatx16 z16 = {0,0,0,0,0,0,0,0,0,0,0,0,0,0,0,0};
  floatx16 acc = z16;          // O^T[dh=(r&3)+8*(r>>2)+4*hi][q=ql]
  float m = -1e30f, l = 0.f;

  // per-lane base pointers (advance per tile)
  const unsigned short* kp = Kh + ((size_t)t0 * 64 + ql) * DHEAD + hi * 8;
  const unsigned short* vp = Vh + (size_t)ql * L_SEQ + t0 * 64 + hi * 4;

  for (int t = t0; t < tend; ++t) {
    // ---- loads (K: 4x16B, V: 8x8B) issued up front ----
    ushort8 kf00 = *(const ushort8*)(kp);               // kg0, d 0..15
    ushort8 kf01 = *(const ushort8*)(kp + 16);          // kg0, d 16..31
    ushort8 kf10 = *(const ushort8*)(kp + 1024);        // kg1, d 0..15
    ushort8 kf11 = *(const ushort8*)(kp + 1024 + 16);   // kg1, d 16..31
    ushort4v v00a = *(const ushort4v*)(vp);             // kg0 sub0: kv' 4hi+0..3
    ushort4v v00b = *(const ushort4v*)(vp + 8);         //          kv' 4hi+8..11
    ushort4v v01a = *(const ushort4v*)(vp + 16);        // kg0 sub1
    ushort4v v01b = *(const ushort4v*)(vp + 24);
    ushort4v v10a = *(const ushort4v*)(vp + 32);        // kg1 sub0
    ushort4v v10b = *(const ushort4v*)(vp + 40);
    ushort4v v11a = *(const ushort4v*)(vp + 48);        // kg1 sub1
    ushort4v v11b = *(const ushort4v*)(vp + 56);
    kp += 64 * DHEAD;
    vp += 64;

    // ---- QK^T: St[kg][row kv'=(r&3)+8*(r>>2)+4*hi][col q=ql] ----
    floatx16 St0 = MFMA32(kf00, qf0, z16);
    St0 = MFMA32(kf01, qf1, St0);
    floatx16 St1 = MFMA32(kf10, qf0, z16);
    St1 = MFMA32(kf11, qf1, St1);

    // ---- lane-local softmax (column q = ql) ----
    float pmax = St0[0];
    #pragma unroll
    for (int i = 1; i < 16; ++i) pmax = fmaxf(pmax, St0[i]);
    #pragma unroll
    for (int i = 0; i < 16; ++i) pmax = fmaxf(pmax, St1[i]);
    pmax = fmaxf(pmax, __shfl_xor(pmax, 32));

    if (__any(pmax > m + 8.0f)) {            // defer-max (THR=8)
      float mnew = fmaxf(m, pmax);
      float corr = __expf(m - mnew);
      m = mnew;
      l *= corr;
      #pragma unroll
      for (int i = 0; i < 16; ++i) acc[i] *= corr;
    }
    float rsum = 0.f;
    #pragma unroll
    for (int i = 0; i < 16; ++i) { float e = __expf(St0[i] - m); St0[i] = e; rsum += e; }
    #pragma unroll
    for (int i = 0; i < 16; ++i) { float e = __expf(St1[i] - m); St1[i] = e; rsum += e; }
    rsum += __shfl_xor(rsum, 32);
    l += rsum;

    // ---- pack P (own lanes only; kv order permuted to match V frags) ----
    uintx4 pb;
    ushort8 va;
    // kg0 sub0: p rows St0[0..7]
    pb[0] = pkbf(St0[0], St0[1]); pb[1] = pkbf(St0[2], St0[3]);
    pb[2] = pkbf(St0[4], St0[5]); pb[3] = pkbf(St0[6], St0[7]);
    va = __builtin_shufflevector(v00a, v00b, 0,1,2,3,4,5,6,7);
    acc = MFMA32(va, __builtin_bit_cast(ushort8, pb), acc);
    // kg0 sub1: St0[8..15]
    pb[0] = pkbf(St0[8], St0[9]);  pb[1] = pkbf(St0[10], St0[11]);
    pb[2] = pkbf(St0[12], St0[13]); pb[3] = pkbf(St0[14], St0[15]);
    va = __builtin_shufflevector(v01a, v01b, 0,1,2,3,4,5,6,7);
    acc = MFMA32(va, __builtin_bit_cast(ushort8, pb), acc);
    // kg1 sub0: St1[0..7]
    pb[0] = pkbf(St1[0], St1[1]); pb[1] = pkbf(St1[2], St1[3]);
    pb[2] = pkbf(St1[4], St1[5]); pb[3] = pkbf(St1[6], St1[7]);
    va = __builtin_shufflevector(v10a, v10b, 0,1,2,3,4,5,6,7);
    acc = MFMA32(va, __builtin_bit_cast(ushort8, pb), acc);
    // kg1 sub1: St1[8..15]
    pb[0] = pkbf(St1[8], St1[9]);  pb[1] = pkbf(St1[10], St1[11]);
    pb[2] = pkbf(St1[12], St1[13]); pb[3] = pkbf(St1[14], St1[15]);
    va = __builtin_shufflevector(v11a, v11b, 0,1,2,3,4,5,6,7);
    acc = MFMA32(va, __builtin_bit_cast(ushort8, pb), acc);
  }

  // ---- epilogue: transpose O^T -> O via LDS, write f32 partials ----
  const int slot = ((plane * 64 + tq) * 4 + c);
  float* T = &Tr[w][0];
  #pragma unroll
  for (int r = 0; r < 16; ++r) {
    int dh = (r & 3) + 8 * (r >> 2) + 4 * hi;
    T[ql * 36 + dh] = acc[r];
  }
  asm volatile("s_waitcnt lgkmcnt(0)" ::: "memory");
  __builtin_amdgcn_sched_barrier(0);

  const int qr = lane >> 1, dg = (lane & 1) * 16;
  float* __restrict__ Op = Opart + (size_t)slot * 2048 + half * 32 * 32;
  #pragma unroll
  for (int j = 0; j < 4; ++j) {
    floatx4 vv = *(const floatx4*)(T + qr * 36 + dg + 4 * j);
    *(floatx4*)(Op + qr * 32 + dg + 4 * j) = vv;
  }
  if (hi == 0) {
    MLpart[(size_t)slot * 128 + (half * 32 + ql) * 2 + 0] = m;
    MLpart[(size_t)slot * 128 + (half * 32 + ql) * 2 + 1] = l;
  }
}

// ---------------------------------------------------------------------------
// Kernel 2b: combine partials -> ctx bf16 [B][L][128]
// Grid (64, 8), 256 threads: thread = (q row 0..63) x (dh-group of 8)
// ---------------------------------------------------------------------------
__global__ __launch_bounds__(256) void combine_kernel(
    const float* __restrict__ Opart, const float* __restrict__ MLpart,
    unsigned short* __restrict__ ctx)
{
  const int tq = blockIdx.x;
  const int hb = blockIdx.y;
  const int nc = (tq >> 4) + 1;
  const int tid = threadIdx.x;
  const int q  = tid >> 2;
  const int dg = tid & 3;
  const int slot0 = (hb * 64 + tq) * 4;

  float mv[4], lv[4];
  float M = -1e30f;
  #pragma unroll
  for (int ci = 0; ci < 4; ++ci) {
    if (ci < nc) {
      mv[ci] = MLpart[(size_t)(slot0 + ci) * 128 + q * 2 + 0];
      lv[ci] = MLpart[(size_t)(slot0 + ci) * 128 + q * 2 + 1];
      M = fmaxf(M, mv[ci]);
    }
  }
  float Lsum = 0.f;
  float wgt[4];
  #pragma unroll
  for (int ci = 0; ci < 4; ++ci) {
    if (ci < nc) {
      wgt[ci] = __expf(mv[ci] - M);
      Lsum += wgt[ci] * lv[ci];
    }
  }
  float inv = 1.0f / Lsum;

  floatx4 a0 = (floatx4){0.f,0.f,0.f,0.f}, a1 = (floatx4){0.f,0.f,0.f,0.f};
  #pragma unroll
  for (int ci = 0; ci < 4; ++ci) {
    if (ci < nc) {
      const float* Op = Opart + (size_t)(slot0 + ci) * 2048 + q * 32 + dg * 8;
      floatx4 o0 = *(const floatx4*)(Op);
      floatx4 o1 = *(const floatx4*)(Op + 4);
      float wv = wgt[ci];
      a0 += wv * o0;
      a1 += wv * o1;
    }
  }
  const int b = hb >> 2, hh = hb & 3;
  size_t base = ((size_t)b * L_SEQ + tq * 64 + q) * DMODEL + hh * 32 + dg * 8;
  #pragma unroll
  for (int j = 0; j < 4; ++j) {
    ctx[base + j]     = f2bf(a0[j] * inv);
    ctx[base + 4 + j] = f2bf(a1[j] * inv);
  }
}

// ---------------------------------------------------------------------------
// Kernel 3: output projection  out = ctx @ W_O^T + b_O  (f32 out)
// ---------------------------------------------------------------------------
__global__ __launch_bounds__(256) void oproj_kernel(
    const unsigned short* __restrict__ ctx, const float* __restrict__ WO,
    const float* __restrict__ bO, float* __restrict__ out)
{
  __shared__ unsigned short Wl[128 * WLDS];
  __shared__ float bl[128];
  const int m0 = blockIdx.x * 64;
  const int tid = threadIdx.x;

  #pragma unroll
  for (int it = 0; it < 16; ++it) {
    int idx = tid + it * 256;
    int row = idx >> 5, col = (idx & 31) * 4;
    floatx4 v = *(const floatx4*)(WO + row * 128 + col);
    unsigned short* dst = Wl + row * WLDS + col;
    dst[0] = f2bf(v[0]); dst[1] = f2bf(v[1]);
    dst[2] = f2bf(v[2]); dst[3] = f2bf(v[3]);
  }
  if (tid < 128) bl[tid] = bO[tid];
  __syncthreads();

  const int w = tid >> 6, lane = tid & 63;
  const int g = lane >> 4, qi = lane & 15;

  ushort8 xf[4];
  #pragma unroll
  for (int kk = 0; kk < 4; ++kk)
    xf[kk] = *(const ushort8*)(ctx + (size_t)(m0 + w * 16 + qi) * DMODEL + kk * 32 + g * 8);

  floatx4 acc[8];
  #pragma unroll
  for (int n = 0; n < 8; ++n) acc[n] = (floatx4){0.f, 0.f, 0.f, 0.f};

  #pragma unroll
  for (int kk = 0; kk < 4; ++kk) {
    #pragma unroll
    for (int n = 0; n < 8; ++n) {
      ushort8 wf = *(const ushort8*)(Wl + (n * 16 + qi) * WLDS + kk * 32 + g * 8);
      acc[n] = MFMA(xf[kk], wf, acc[n]);
    }
  }

  #pragma unroll
  for (int n = 0; n < 8; ++n) {
    int c = n * 16 + qi;
    float bb = bl[c];
    #pragma unroll
    for (int r = 0; r < 4; ++r) {
      int m = m0 + w * 16 + 4 * g + r;
      out[(size_t)m * DMODEL + c] = acc[n][r] + bb;
    }
  }
}

// ---------------------------------------------------------------------------
extern "C" void kernel_launch(void* const* d_in, const int* in_sizes, int n_in,
                              void* d_out, int out_size, void* d_ws, size_t ws_size,
                              hipStream_t stream) {
  const float* q  = (const float*)d_in[0];
  const float* k  = (const float*)d_in[1];
  const float* v  = (const float*)d_in[2];
  const float* WQ = (const float*)d_in[3];
  const float* bQ = (const float*)d_in[4];
  const float* WK = (const float*)d_in[5];
  const float* bK = (const float*)d_in[6];
  const float* WV = (const float*)d_in[7];
  const float* bV = (const float*)d_in[8];
  const float* WO = (const float*)d_in[9];
  const float* bO = (const float*)d_in[10];
  float* out = (float*)d_out;

  const size_t plane = (size_t)BATCH * NHEAD * L_SEQ * DHEAD;  // 1,048,576 ush
  unsigned short* Qs  = (unsigned short*)d_ws;
  unsigned short* Ks  = Qs + plane;
  unsigned short* Vt  = Ks + plane;
  unsigned short* ctx = Vt + plane;                 // [B][L][128] bf16 (1M ush)
  float* Opart  = (float*)(ctx + plane);            // 2048 slots x 64 x 32 f32
  float* MLpart = Opart + (size_t)2048 * 2048;      // 2048 slots x 64 x 2 f32

  hipLaunchKernelGGL(proj_kernel, dim3(64, 2, 3), dim3(256), 0, stream,
                     q, k, v, WQ, bQ, WK, bK, WV, bV, Qs, Ks, Vt);
  hipLaunchKernelGGL(attn_kernel, dim3(40, 16), dim3(256), 0, stream,
                     Qs, Ks, Vt, Opart, MLpart);
  hipLaunchKernelGGL(combine_kernel, dim3(64, 8), dim3(256), 0, stream,
                     Opart, MLpart, ctx);
  hipLaunchKernelGGL(oproj_kernel, dim3(128), dim3(256), 0, stream, ctx, WO, bO, out);
}

// Round 9
// 47.927 us; speedup vs baseline: 2.0699x; 1.6464x over previous
//
#include <hip/hip_runtime.h>

#define L_SEQ 4096
#define BATCH 2
#define NHEAD 4
#define DHEAD 32
#define DMODEL 128
#define CH 16            // kv tiles (of 64) per chunk -> <=4 chunks per q-tile

typedef __attribute__((ext_vector_type(4))) float floatx4;
typedef __attribute__((ext_vector_type(16))) float floatx16;
typedef __attribute__((ext_vector_type(8))) __bf16 bf16x8;
typedef __attribute__((ext_vector_type(8))) unsigned short ushort8;
typedef __attribute__((ext_vector_type(4))) unsigned int uintx4;

__device__ __forceinline__ floatx4 MFMA(ushort8 a, ushort8 b, floatx4 c) {
  return __builtin_amdgcn_mfma_f32_16x16x32_bf16(
      __builtin_bit_cast(bf16x8, a), __builtin_bit_cast(bf16x8, b), c, 0, 0, 0);
}
__device__ __forceinline__ floatx16 MFMA32(ushort8 a, ushort8 b, floatx16 c) {
  return __builtin_amdgcn_mfma_f32_32x32x16_bf16(
      __builtin_bit_cast(bf16x8, a), __builtin_bit_cast(bf16x8, b), c, 0, 0, 0);
}

__device__ __forceinline__ unsigned short f2bf(float f) {
  union { float f; unsigned int u; } x; x.f = f;
  unsigned int u = x.u + 0x7fffu + ((x.u >> 16) & 1u);   // RNE truncate
  return (unsigned short)(u >> 16);
}

__device__ __forceinline__ unsigned pkbf(float lo, float hi) {
  unsigned r;
  asm("v_cvt_pk_bf16_f32 %0, %1, %2" : "=v"(r) : "v"(lo), "v"(hi));
  return r;
}

// ---------------------------------------------------------------------------
// Kernel 1: fused QKV projection.  out = x @ W^T + b  (Q also * 1/sqrt(32))
// Q stored natural [plane][L][32] bf16.
// K,V stored FRAGMENT-PACKED per 64-kv tile: [plane][t][frag 0..3][lane][8]
//   K frag j (=2*rhi+dj): lane (hi*32+ql) holds K[t*64+rhi*32+ql][dj*16+hi*8+e]
//   V frag s:             lane (hi*32+dh) holds V^T[dh][t*64 + {16s+4hi+e, 16s+8+4hi+e}]
// so attn's per-lane ushort8 loads are base + lane*16B (fully coalesced).
// ---------------------------------------------------------------------------
#define WLDS 136

__global__ __launch_bounds__(256) void proj_kernel(
    const float* __restrict__ xq, const float* __restrict__ xk,
    const float* __restrict__ xv,
    const float* __restrict__ WQ, const float* __restrict__ bQ,
    const float* __restrict__ WK, const float* __restrict__ bK,
    const float* __restrict__ WV, const float* __restrict__ bV,
    unsigned short* __restrict__ Qs, unsigned short* __restrict__ Ks,
    unsigned short* __restrict__ Vt)
{
  __shared__ unsigned short Wl[128 * WLDS];
  __shared__ float bl[128];
  const int mat = blockIdx.z;
  const int b   = blockIdx.y;
  const int l0  = blockIdx.x * 64;
  const float* __restrict__ x    = (mat == 0) ? xq : (mat == 1) ? xk : xv;
  const float* __restrict__ W    = (mat == 0) ? WQ : (mat == 1) ? WK : WV;
  const float* __restrict__ bias = (mat == 0) ? bQ : (mat == 1) ? bK : bV;
  const int tid = threadIdx.x;

  #pragma unroll
  for (int it = 0; it < 16; ++it) {
    int idx = tid + it * 256;
    int row = idx >> 5;
    int col = (idx & 31) * 4;
    floatx4 v = *(const floatx4*)(W + row * 128 + col);
    unsigned short* dst = Wl + row * WLDS + col;
    dst[0] = f2bf(v[0]); dst[1] = f2bf(v[1]);
    dst[2] = f2bf(v[2]); dst[3] = f2bf(v[3]);
  }
  if (tid < 128) bl[tid] = bias[tid];
  __syncthreads();

  const int w = tid >> 6, lane = tid & 63;
  const int g = lane >> 4, qi = lane & 15;

  ushort8 xf[4];
  #pragma unroll
  for (int kk = 0; kk < 4; ++kk) {
    const float* src = x + ((size_t)(l0 + w * 16 + qi) * BATCH + b) * DMODEL + kk * 32 + g * 8;
    floatx4 a = *(const floatx4*)src;
    floatx4 c = *(const floatx4*)(src + 4);
    ushort8 f;
    f[0]=f2bf(a[0]); f[1]=f2bf(a[1]); f[2]=f2bf(a[2]); f[3]=f2bf(a[3]);
    f[4]=f2bf(c[0]); f[5]=f2bf(c[1]); f[6]=f2bf(c[2]); f[7]=f2bf(c[3]);
    xf[kk] = f;
  }

  floatx4 acc[8];
  #pragma unroll
  for (int n = 0; n < 8; ++n) acc[n] = (floatx4){0.f, 0.f, 0.f, 0.f};

  #pragma unroll
  for (int kk = 0; kk < 4; ++kk) {
    #pragma unroll
    for (int n = 0; n < 8; ++n) {
      ushort8 wf = *(const ushort8*)(Wl + (n * 16 + qi) * WLDS + kk * 32 + g * 8);
      acc[n] = (mat == 2) ? MFMA(wf, xf[kk], acc[n]) : MFMA(xf[kk], wf, acc[n]);
    }
  }

  const int hb4 = b * NHEAD;
  if (mat == 0) {
    // Q natural layout (loaded once per wave in attn; coalescing there is moot)
    const float scale = 0.17677669529663687f;  // 32^-0.5
    #pragma unroll
    for (int n = 0; n < 8; ++n) {
      int c = n * 16 + qi;
      int h = c >> 5, dh = c & 31;
      float bb = bl[c];
      #pragma unroll
      for (int r = 0; r < 4; ++r) {
        int lq = l0 + w * 16 + 4 * g + r;
        float v = (acc[n][r] + bb) * scale;
        Qs[((size_t)(hb4 + h) * L_SEQ + lq) * DHEAD + dh] = f2bf(v);
      }
    }
  } else if (mat == 1) {
    // K fragment-packed
    #pragma unroll
    for (int n = 0; n < 8; ++n) {
      int c = n * 16 + qi;
      int h = c >> 5, dh = c & 31;
      int dj  = (dh >> 4) & 1;
      int hi2 = (dh >> 3) & 1;
      int e   = dh & 7;
      float bb = bl[c];
      #pragma unroll
      for (int r = 0; r < 4; ++r) {
        int lq = l0 + w * 16 + 4 * g + r;
        int t   = lq >> 6;
        int rr  = lq & 63;
        int ql2 = rr & 31, rhi = rr >> 5;
        size_t off = ((((size_t)(hb4 + h) * 64 + t) * 4 + (2 * rhi + dj)) * 64
                      + (hi2 * 32 + ql2)) * 8 + e;
        Ks[off] = f2bf(acc[n][r] + bb);
      }
    }
  } else {
    // V fragment-packed
    #pragma unroll
    for (int n = 0; n < 8; ++n) {
      #pragma unroll
      for (int r = 0; r < 4; ++r) {
        int cout = n * 16 + 4 * g + r;
        int h = cout >> 5, dh2 = cout & 31;
        float v = acc[n][r] + bl[cout];
        int lq  = l0 + w * 16 + qi;
        int t   = lq >> 6;
        int kvt = lq & 63;
        int s   = kvt >> 4;
        int u   = kvt & 15;
        int b2  = (u >> 3) & 1;
        int hi2 = (u >> 2) & 1;
        int e2  = u & 3;
        size_t off = ((((size_t)(hb4 + h) * 64 + t) * 4 + s) * 64
                      + (hi2 * 32 + dh2)) * 8 + (4 * b2 + e2);
        Vt[off] = f2bf(v);
      }
    }
  }
}

// ---------------------------------------------------------------------------
// Kernel 2: KV-split flash attention, 32x32 MFMA, fully lane-local softmax.
// Identical structure/geometry/math to the green R8 kernel; ONLY the K/V
// load addresses changed to the fragment-packed layout (base + lane*16B,
// fully coalesced, 2048 ush per tile, frag stride 512 ush).
// Grid (40, 16): x*4+wave = chunk id (0..159), y = plane*2 + half.
// ---------------------------------------------------------------------------
__global__ __launch_bounds__(256, 4) void attn_kernel(
    const unsigned short* __restrict__ Qs, const unsigned short* __restrict__ Ks,
    const unsigned short* __restrict__ Vt,
    float* __restrict__ Opart, float* __restrict__ MLpart)
{
  __shared__ float Tr[4][32 * 36];   // per-wave transpose scratch

  const int tid = threadIdx.x;
  const int w = tid >> 6, lane = tid & 63;
  const int ql = lane & 31, hi = lane >> 5;

  const int cid   = blockIdx.x * 4 + w;      // 0..159
  const int plane = blockIdx.y >> 1;
  const int half  = blockIdx.y & 1;

  int c, tq;
  if (cid < 64)       { c = 0; tq = cid; }
  else if (cid < 112) { c = 1; tq = cid - 48; }
  else if (cid < 144) { c = 2; tq = cid - 80; }
  else                { c = 3; tq = cid - 96; }
  const int t0   = c * CH;
  const int tend = min(t0 + CH, tq + 1);

  const unsigned short* __restrict__ Qh = Qs + (size_t)plane * L_SEQ * DHEAD;

  const int q0 = tq * 64 + half * 32;
  // Q B-frags: lane holds Q[q0+ql][dhalf*16 + hi*8 + 0..7]
  ushort8 qf0 = *(const ushort8*)(Qh + (size_t)(q0 + ql) * DHEAD + hi * 8);
  ushort8 qf1 = *(const ushort8*)(Qh + (size_t)(q0 + ql) * DHEAD + 16 + hi * 8);

  const floatx16 z16 = {0,0,0,0,0,0,0,0,0,0,0,0,0,0,0,0};
  floatx16 acc = z16;          // O^T[dh=(r&3)+8*(r>>2)+4*hi][q=ql]
  float m = -1e30f, l = 0.f;

  // fragment-packed tile base pointers (advance 2048 ush per tile)
  const unsigned short* kb = Ks + ((size_t)plane * 64 + t0) * 2048 + (size_t)lane * 8;
  const unsigned short* vb = Vt + ((size_t)plane * 64 + t0) * 2048 + (size_t)lane * 8;

  for (int t = t0; t < tend; ++t) {
    // ---- loads: 8 x fully-coalesced 16B/lane ----
    ushort8 kf00 = *(const ushort8*)(kb);           // j0: rows 0-31,  d 0..15
    ushort8 kf01 = *(const ushort8*)(kb + 512);     // j1: rows 0-31,  d 16..31
    ushort8 kf10 = *(const ushort8*)(kb + 1024);    // j2: rows 32-63, d 0..15
    ushort8 kf11 = *(const ushort8*)(kb + 1536);    // j3: rows 32-63, d 16..31
    ushort8 va0  = *(const ushort8*)(vb);           // s0: kv 0..15
    ushort8 va1  = *(const ushort8*)(vb + 512);     // s1: kv 16..31
    ushort8 va2  = *(const ushort8*)(vb + 1024);    // s2: kv 32..47
    ushort8 va3  = *(const ushort8*)(vb + 1536);    // s3: kv 48..63
    kb += 2048;
    vb += 2048;

    // ---- QK^T: St[kg][row kv'=(r&3)+8*(r>>2)+4*hi][col q=ql] ----
    floatx16 St0 = MFMA32(kf00, qf0, z16);
    St0 = MFMA32(kf01, qf1, St0);
    floatx16 St1 = MFMA32(kf10, qf0, z16);
    St1 = MFMA32(kf11, qf1, St1);

    // ---- lane-local softmax (column q = ql) ----
    float pmax = St0[0];
    #pragma unroll
    for (int i = 1; i < 16; ++i) pmax = fmaxf(pmax, St0[i]);
    #pragma unroll
    for (int i = 0; i < 16; ++i) pmax = fmaxf(pmax, St1[i]);
    pmax = fmaxf(pmax, __shfl_xor(pmax, 32));

    if (__any(pmax > m + 8.0f)) {            // defer-max (THR=8)
      float mnew = fmaxf(m, pmax);
      float corr = __expf(m - mnew);
      m = mnew;
      l *= corr;
      #pragma unroll
      for (int i = 0; i < 16; ++i) acc[i] *= corr;
    }
    float rsum = 0.f;
    #pragma unroll
    for (int i = 0; i < 16; ++i) { float e = __expf(St0[i] - m); St0[i] = e; rsum += e; }
    #pragma unroll
    for (int i = 0; i < 16; ++i) { float e = __expf(St1[i] - m); St1[i] = e; rsum += e; }
    rsum += __shfl_xor(rsum, 32);
    l += rsum;

    // ---- pack P (own lanes only; kv order matches packed V frags) ----
    uintx4 pb;
    // kg0 sub0: p rows St0[0..7]
    pb[0] = pkbf(St0[0], St0[1]); pb[1] = pkbf(St0[2], St0[3]);
    pb[2] = pkbf(St0[4], St0[5]); pb[3] = pkbf(St0[6], St0[7]);
    acc = MFMA32(va0, __builtin_bit_cast(ushort8, pb), acc);
    // kg0 sub1: St0[8..15]
    pb[0] = pkbf(St0[8], St0[9]);  pb[1] = pkbf(St0[10], St0[11]);
    pb[2] = pkbf(St0[12], St0[13]); pb[3] = pkbf(St0[14], St0[15]);
    acc = MFMA32(va1, __builtin_bit_cast(ushort8, pb), acc);
    // kg1 sub0: St1[0..7]
    pb[0] = pkbf(St1[0], St1[1]); pb[1] = pkbf(St1[2], St1[3]);
    pb[2] = pkbf(St1[4], St1[5]); pb[3] = pkbf(St1[6], St1[7]);
    acc = MFMA32(va2, __builtin_bit_cast(ushort8, pb), acc);
    // kg1 sub1: St1[8..15]
    pb[0] = pkbf(St1[8], St1[9]);  pb[1] = pkbf(St1[10], St1[11]);
    pb[2] = pkbf(St1[12], St1[13]); pb[3] = pkbf(St1[14], St1[15]);
    acc = MFMA32(va3, __builtin_bit_cast(ushort8, pb), acc);
  }

  // ---- epilogue: transpose O^T -> O via LDS, write f32 partials ----
  const int slot = ((plane * 64 + tq) * 4 + c);
  float* T = &Tr[w][0];
  #pragma unroll
  for (int r = 0; r < 16; ++r) {
    int dh = (r & 3) + 8 * (r >> 2) + 4 * hi;
    T[ql * 36 + dh] = acc[r];
  }
  asm volatile("s_waitcnt lgkmcnt(0)" ::: "memory");
  __builtin_amdgcn_sched_barrier(0);

  const int qr = lane >> 1, dg = (lane & 1) * 16;
  float* __restrict__ Op = Opart + (size_t)slot * 2048 + half * 32 * 32;
  #pragma unroll
  for (int j = 0; j < 4; ++j) {
    floatx4 vv = *(const floatx4*)(T + qr * 36 + dg + 4 * j);
    *(floatx4*)(Op + qr * 32 + dg + 4 * j) = vv;
  }
  if (hi == 0) {
    MLpart[(size_t)slot * 128 + (half * 32 + ql) * 2 + 0] = m;
    MLpart[(size_t)slot * 128 + (half * 32 + ql) * 2 + 1] = l;
  }
}

// ---------------------------------------------------------------------------
// Kernel 2b: combine partials -> ctx bf16 [B][L][128]
// Grid (64, 8), 256 threads: thread = (q row 0..63) x (dh-group of 8)
// ---------------------------------------------------------------------------
__global__ __launch_bounds__(256) void combine_kernel(
    const float* __restrict__ Opart, const float* __restrict__ MLpart,
    unsigned short* __restrict__ ctx)
{
  const int tq = blockIdx.x;
  const int hb = blockIdx.y;
  const int nc = (tq >> 4) + 1;
  const int tid = threadIdx.x;
  const int q  = tid >> 2;
  const int dg = tid & 3;
  const int slot0 = (hb * 64 + tq) * 4;

  float mv[4], lv[4];
  float M = -1e30f;
  #pragma unroll
  for (int ci = 0; ci < 4; ++ci) {
    if (ci < nc) {
      mv[ci] = MLpart[(size_t)(slot0 + ci) * 128 + q * 2 + 0];
      lv[ci] = MLpart[(size_t)(slot0 + ci) * 128 + q * 2 + 1];
      M = fmaxf(M, mv[ci]);
    }
  }
  float Lsum = 0.f;
  float wgt[4];
  #pragma unroll
  for (int ci = 0; ci < 4; ++ci) {
    if (ci < nc) {
      wgt[ci] = __expf(mv[ci] - M);
      Lsum += wgt[ci] * lv[ci];
    }
  }
  float inv = 1.0f / Lsum;

  floatx4 a0 = (floatx4){0.f,0.f,0.f,0.f}, a1 = (floatx4){0.f,0.f,0.f,0.f};
  #pragma unroll
  for (int ci = 0; ci < 4; ++ci) {
    if (ci < nc) {
      const float* Op = Opart + (size_t)(slot0 + ci) * 2048 + q * 32 + dg * 8;
      floatx4 o0 = *(const floatx4*)(Op);
      floatx4 o1 = *(const floatx4*)(Op + 4);
      float wv = wgt[ci];
      a0 += wv * o0;
      a1 += wv * o1;
    }
  }
  const int b = hb >> 2, hh = hb & 3;
  size_t base = ((size_t)b * L_SEQ + tq * 64 + q) * DMODEL + hh * 32 + dg * 8;
  #pragma unroll
  for (int j = 0; j < 4; ++j) {
    ctx[base + j]     = f2bf(a0[j] * inv);
    ctx[base + 4 + j] = f2bf(a1[j] * inv);
  }
}

// ---------------------------------------------------------------------------
// Kernel 3: output projection  out = ctx @ W_O^T + b_O  (f32 out)
// ---------------------------------------------------------------------------
__global__ __launch_bounds__(256) void oproj_kernel(
    const unsigned short* __restrict__ ctx, const float* __restrict__ WO,
    const float* __restrict__ bO, float* __restrict__ out)
{
  __shared__ unsigned short Wl[128 * WLDS];
  __shared__ float bl[128];
  const int m0 = blockIdx.x * 64;
  const int tid = threadIdx.x;

  #pragma unroll
  for (int it = 0; it < 16; ++it) {
    int idx = tid + it * 256;
    int row = idx >> 5, col = (idx & 31) * 4;
    floatx4 v = *(const floatx4*)(WO + row * 128 + col);
    unsigned short* dst = Wl + row * WLDS + col;
    dst[0] = f2bf(v[0]); dst[1] = f2bf(v[1]);
    dst[2] = f2bf(v[2]); dst[3] = f2bf(v[3]);
  }
  if (tid < 128) bl[tid] = bO[tid];
  __syncthreads();

  const int w = tid >> 6, lane = tid & 63;
  const int g = lane >> 4, qi = lane & 15;

  ushort8 xf[4];
  #pragma unroll
  for (int kk = 0; kk < 4; ++kk)
    xf[kk] = *(const ushort8*)(ctx + (size_t)(m0 + w * 16 + qi) * DMODEL + kk * 32 + g * 8);

  floatx4 acc[8];
  #pragma unroll
  for (int n = 0; n < 8; ++n) acc[n] = (floatx4){0.f, 0.f, 0.f, 0.f};

  #pragma unroll
  for (int kk = 0; kk < 4; ++kk) {
    #pragma unroll
    for (int n = 0; n < 8; ++n) {
      ushort8 wf = *(const ushort8*)(Wl + (n * 16 + qi) * WLDS + kk * 32 + g * 8);
      acc[n] = MFMA(xf[kk], wf, acc[n]);
    }
  }

  #pragma unroll
  for (int n = 0; n < 8; ++n) {
    int c = n * 16 + qi;
    float bb = bl[c];
    #pragma unroll
    for (int r = 0; r < 4; ++r) {
      int m = m0 + w * 16 + 4 * g + r;
      out[(size_t)m * DMODEL + c] = acc[n][r] + bb;
    }
  }
}

// ---------------------------------------------------------------------------
extern "C" void kernel_launch(void* const* d_in, const int* in_sizes, int n_in,
                              void* d_out, int out_size, void* d_ws, size_t ws_size,
                              hipStream_t stream) {
  const float* q  = (const float*)d_in[0];
  const float* k  = (const float*)d_in[1];
  const float* v  = (const float*)d_in[2];
  const float* WQ = (const float*)d_in[3];
  const float* bQ = (const float*)d_in[4];
  const float* WK = (const float*)d_in[5];
  const float* bK = (const float*)d_in[6];
  const float* WV = (const float*)d_in[7];
  const float* bV = (const float*)d_in[8];
  const float* WO = (const float*)d_in[9];
  const float* bO = (const float*)d_in[10];
  float* out = (float*)d_out;

  const size_t plane = (size_t)BATCH * NHEAD * L_SEQ * DHEAD;  // 1,048,576 ush
  unsigned short* Qs  = (unsigned short*)d_ws;
  unsigned short* Ks  = Qs + plane;
  unsigned short* Vt  = Ks + plane;
  unsigned short* ctx = Vt + plane;                 // [B][L][128] bf16 (1M ush)
  float* Opart  = (float*)(ctx + plane);            // 2048 slots x 64 x 32 f32
  float* MLpart = Opart + (size_t)2048 * 2048;      // 2048 slots x 64 x 2 f32

  hipLaunchKernelGGL(proj_kernel, dim3(64, 2, 3), dim3(256), 0, stream,
                     q, k, v, WQ, bQ, WK, bK, WV, bV, Qs, Ks, Vt);
  hipLaunchKernelGGL(attn_kernel, dim3(40, 16), dim3(256), 0, stream,
                     Qs, Ks, Vt, Opart, MLpart);
  hipLaunchKernelGGL(combine_kernel, dim3(64, 8), dim3(256), 0, stream,
                     Opart, MLpart, ctx);
  hipLaunchKernelGGL(oproj_kernel, dim3(128), dim3(256), 0, stream, ctx, WO, bO, out);
}